// Round 1
// baseline (665.951 us; speedup 1.0000x reference)
//
#include <hip/hip_runtime.h>
#include <math.h>

#define F 128
#define NLAYERS 2

typedef __attribute__((ext_vector_type(8))) short bf16x8s;
typedef __attribute__((ext_vector_type(4))) float f32x4;

__device__ __forceinline__ float sigmoidf_(float x) { return 1.0f / (1.0f + expf(-x)); }

__device__ __forceinline__ unsigned short f2bf(float f) {
    unsigned int u = __float_as_uint(f);
    u += 0x7fffu + ((u >> 16) & 1u);  // RNE
    return (unsigned short)(u >> 16);
}
__device__ __forceinline__ float bf2f(unsigned short s) {
    return __uint_as_float(((unsigned int)s) << 16);
}

// ---------------------------------------------------------------------------
// Weight pack: f32 [L][3][256][128] -> bf16 k-octet layout.
//  W1b [L][64][256][8]: gates (r|u) as 256 cols, K=512 parts (x,h,agg_x,agg_h)
//  W2b [L][64][128][8]: gate c, K parts (x, rh, agg_x, agg_rh)
// ---------------------------------------------------------------------------
__global__ void pack_w_bf16(const float* __restrict__ Ws, const float* __restrict__ Wn,
                            unsigned short* __restrict__ W1b, unsigned short* __restrict__ W2b) {
    int t = blockIdx.x * blockDim.x + threadIdx.x;
    const int n1 = 2 * 64 * 256 * 8;  // 262144
    if (t < n1) {
        int j = t & 7, n = (t >> 3) & 255, ko = (t >> 11) & 63, l = t >> 17;
        int k = ko * 8 + j;
        int p = k >> 7, r = k & 127, g = n >> 7, c = n & 127;
        const float* W = (p < 2) ? Ws : Wn;
        W1b[t] = f2bf(W[(((l * 3 + g) * 256) + ((p & 1) * 128 + r)) * 128 + c]);
    } else {
        int t2 = t - n1;
        if (t2 >= 2 * 64 * 128 * 8) return;
        int j = t2 & 7, n = (t2 >> 3) & 127, ko = (t2 >> 10) & 63, l = t2 >> 16;
        int k = ko * 8 + j;
        int p = k >> 7, r = k & 127;
        const float* W = (p < 2) ? Ws : Wn;
        W2b[t2] = f2bf(W[(((l * 3 + 2) * 256) + ((p & 1) * 128 + r)) * 128 + n]);
    }
}

// f32 -> bf16 row-major copy (float4 in, ushort4 out)
__global__ void cvt_bf16(const float* __restrict__ in, unsigned short* __restrict__ out, int n4) {
    int t = blockIdx.x * blockDim.x + threadIdx.x;
    if (t >= n4) return;
    float4 v = reinterpret_cast<const float4*>(in)[t];
    ushort4 o;
    o.x = f2bf(v.x); o.y = f2bf(v.y); o.z = f2bf(v.z); o.w = f2bf(v.w);
    reinterpret_cast<ushort4*>(out)[t] = o;
}

// ---------------------------------------------------------------------------
// CSR build
// ---------------------------------------------------------------------------
__global__ void hist_dst(const int* __restrict__ dst, int* __restrict__ cnt, int E) {
    int e = blockIdx.x * blockDim.x + threadIdx.x;
    if (e < E) atomicAdd(&cnt[dst[e]], 1);
}

__global__ __launch_bounds__(1024) void scan_offs(const int* __restrict__ cnt,
                                                  int* __restrict__ offs,
                                                  int* __restrict__ cursor, int n) {
    __shared__ int wsum[16];
    __shared__ int carry_s;
    int tid = threadIdx.x;
    int lane = tid & 63, wid = tid >> 6;
    if (tid == 0) carry_s = 0;
    __syncthreads();
    for (int base = 0; base < n; base += 1024) {
        int i = base + tid;
        int v = (i < n) ? cnt[i] : 0;
        int incl = v;
#pragma unroll
        for (int off = 1; off < 64; off <<= 1) {
            int t = __shfl_up(incl, off, 64);
            if (lane >= off) incl += t;
        }
        if (lane == 63) wsum[wid] = incl;
        __syncthreads();
        if (wid == 0) {
            int s = (lane < 16) ? wsum[lane] : 0;
#pragma unroll
            for (int off = 1; off < 16; off <<= 1) {
                int t = __shfl_up(s, off, 64);
                if (lane >= off) s += t;
            }
            if (lane < 16) wsum[lane] = s;
        }
        __syncthreads();
        int wbase = (wid > 0) ? wsum[wid - 1] : 0;
        int carry = carry_s;
        int excl = carry + wbase + incl - v;
        if (i < n) { offs[i] = excl; cursor[i] = excl; }
        __syncthreads();
        if (tid == 1023) carry_s = carry + wsum[15];
        __syncthreads();
    }
    if (threadIdx.x == 0) offs[n] = carry_s;
}

__global__ void scatter_edges(const int* __restrict__ src, const int* __restrict__ dst,
                              const float* __restrict__ ew, int* __restrict__ cursor,
                              int2* __restrict__ es, int E) {
    int e = blockIdx.x * blockDim.x + threadIdx.x;
    if (e >= E) return;
    int d = dst[e];
    int p = atomicAdd(&cursor[d], 1);
    es[p] = make_int2(src[e], __float_as_int(ew[e]));
}

// ---------------------------------------------------------------------------
// CSR aggregation over bf16 tables: 32 lanes/node, ushort4 (8B) per lane,
// unroll-2 with dual accumulators for MLP. f32 accumulate, bf16 store.
// ---------------------------------------------------------------------------
__global__ __launch_bounds__(256) void agg_csr2_b(
    const unsigned short* __restrict__ V0, const unsigned short* __restrict__ V1,
    const int2* __restrict__ es, const int* __restrict__ offs,
    unsigned short* __restrict__ agg0, unsigned short* __restrict__ agg1, int N) {
    int node = blockIdx.x * 8 + (threadIdx.x >> 5);
    if (node >= N) return;
    int lane = threadIdx.x & 31;
    int beg = offs[node], end = offs[node + 1];
    float p0[4] = {0, 0, 0, 0}, q0[4] = {0, 0, 0, 0};
    float p1[4] = {0, 0, 0, 0}, q1[4] = {0, 0, 0, 0};
    int i = beg;
    for (; i + 1 < end; i += 2) {
        int2 e0 = es[i], e1 = es[i + 1];
        float w0 = __int_as_float(e0.y), w1 = __int_as_float(e1.y);
        size_t r0 = ((size_t)e0.x << 7) + (lane << 2);
        size_t r1 = ((size_t)e1.x << 7) + (lane << 2);
        ushort4 x0 = *reinterpret_cast<const ushort4*>(V0 + r0);
        ushort4 x1 = *reinterpret_cast<const ushort4*>(V0 + r1);
        ushort4 h0 = *reinterpret_cast<const ushort4*>(V1 + r0);
        ushort4 h1 = *reinterpret_cast<const ushort4*>(V1 + r1);
        p0[0] += w0 * bf2f(x0.x); p0[1] += w0 * bf2f(x0.y);
        p0[2] += w0 * bf2f(x0.z); p0[3] += w0 * bf2f(x0.w);
        p1[0] += w1 * bf2f(x1.x); p1[1] += w1 * bf2f(x1.y);
        p1[2] += w1 * bf2f(x1.z); p1[3] += w1 * bf2f(x1.w);
        q0[0] += w0 * bf2f(h0.x); q0[1] += w0 * bf2f(h0.y);
        q0[2] += w0 * bf2f(h0.z); q0[3] += w0 * bf2f(h0.w);
        q1[0] += w1 * bf2f(h1.x); q1[1] += w1 * bf2f(h1.y);
        q1[2] += w1 * bf2f(h1.z); q1[3] += w1 * bf2f(h1.w);
    }
    if (i < end) {
        int2 e0 = es[i];
        float w0 = __int_as_float(e0.y);
        size_t r0 = ((size_t)e0.x << 7) + (lane << 2);
        ushort4 x0 = *reinterpret_cast<const ushort4*>(V0 + r0);
        ushort4 h0 = *reinterpret_cast<const ushort4*>(V1 + r0);
        p0[0] += w0 * bf2f(x0.x); p0[1] += w0 * bf2f(x0.y);
        p0[2] += w0 * bf2f(x0.z); p0[3] += w0 * bf2f(x0.w);
        q0[0] += w0 * bf2f(h0.x); q0[1] += w0 * bf2f(h0.y);
        q0[2] += w0 * bf2f(h0.z); q0[3] += w0 * bf2f(h0.w);
    }
    size_t ob = ((size_t)node << 7) + (lane << 2);
    ushort4 o0, o1;
    o0.x = f2bf(p0[0] + p1[0]); o0.y = f2bf(p0[1] + p1[1]);
    o0.z = f2bf(p0[2] + p1[2]); o0.w = f2bf(p0[3] + p1[3]);
    o1.x = f2bf(q0[0] + q1[0]); o1.y = f2bf(q0[1] + q1[1]);
    o1.z = f2bf(q0[2] + q1[2]); o1.w = f2bf(q0[3] + q1[3]);
    *reinterpret_cast<ushort4*>(agg0 + ob) = o0;
    *reinterpret_cast<ushort4*>(agg1 + ob) = o1;
}

__global__ __launch_bounds__(256) void agg_csr1_b(
    const unsigned short* __restrict__ V0,
    const int2* __restrict__ es, const int* __restrict__ offs,
    unsigned short* __restrict__ agg0, int N) {
    int node = blockIdx.x * 8 + (threadIdx.x >> 5);
    if (node >= N) return;
    int lane = threadIdx.x & 31;
    int beg = offs[node], end = offs[node + 1];
    float p0[4] = {0, 0, 0, 0}, p1[4] = {0, 0, 0, 0};
    int i = beg;
    for (; i + 1 < end; i += 2) {
        int2 e0 = es[i], e1 = es[i + 1];
        float w0 = __int_as_float(e0.y), w1 = __int_as_float(e1.y);
        size_t r0 = ((size_t)e0.x << 7) + (lane << 2);
        size_t r1 = ((size_t)e1.x << 7) + (lane << 2);
        ushort4 x0 = *reinterpret_cast<const ushort4*>(V0 + r0);
        ushort4 x1 = *reinterpret_cast<const ushort4*>(V0 + r1);
        p0[0] += w0 * bf2f(x0.x); p0[1] += w0 * bf2f(x0.y);
        p0[2] += w0 * bf2f(x0.z); p0[3] += w0 * bf2f(x0.w);
        p1[0] += w1 * bf2f(x1.x); p1[1] += w1 * bf2f(x1.y);
        p1[2] += w1 * bf2f(x1.z); p1[3] += w1 * bf2f(x1.w);
    }
    if (i < end) {
        int2 e0 = es[i];
        float w0 = __int_as_float(e0.y);
        size_t r0 = ((size_t)e0.x << 7) + (lane << 2);
        ushort4 x0 = *reinterpret_cast<const ushort4*>(V0 + r0);
        p0[0] += w0 * bf2f(x0.x); p0[1] += w0 * bf2f(x0.y);
        p0[2] += w0 * bf2f(x0.z); p0[3] += w0 * bf2f(x0.w);
    }
    size_t ob = ((size_t)node << 7) + (lane << 2);
    ushort4 o0;
    o0.x = f2bf(p0[0] + p1[0]); o0.y = f2bf(p0[1] + p1[1]);
    o0.z = f2bf(p0[2] + p1[2]); o0.w = f2bf(p0[3] + p1[3]);
    *reinterpret_cast<ushort4*>(agg0 + ob) = o0;
}

// ---------------------------------------------------------------------------
// MFMA GEMM, 64x128 tile, 4 waves (2x2), 2x4 frags/wave, double-buffered LDS.
// A = [A0|A1|A2|A3] (N x 512 bf16, 4 row-major 128-col parts),
// B = Wb bf16 k-octet layout [K/8][Ntot][8].
// mode 0 (ru): col<128 -> rhb = bf16(sigmoid*h); col>=128 -> u = sigmoid (f32)
// mode 1 (c):  c = sigmoid; hn = u*h+(1-u)*c -> outf (+outf2), outb = bf16(hn)
// ---------------------------------------------------------------------------
__global__ __launch_bounds__(256) void gemm_mfma(
    const unsigned short* __restrict__ A0, const unsigned short* __restrict__ A1,
    const unsigned short* __restrict__ A2, const unsigned short* __restrict__ A3,
    const unsigned short* __restrict__ Wb, const float* __restrict__ bias,
    const float* __restrict__ hfull, const float* __restrict__ uin,
    unsigned short* __restrict__ outb, float* __restrict__ outf,
    float* __restrict__ outf2, int Nn, int Ntot, int mode) {
    __shared__ __align__(16) unsigned short Als[2][4 * 64 * 8];   // [buf][q][m][8]  4KB x2
    __shared__ __align__(16) unsigned short Bls[2][4 * 128 * 8];  // [buf][q][n][8]  8KB x2
    const unsigned short* parts[4] = {A0, A1, A2, A3};

    int tid = threadIdx.x;
    int row0 = blockIdx.x * 64;
    int n0c = blockIdx.y * 128;
    int lane = tid & 63;
    int w = tid >> 6;
    int wrow = (w & 1) << 5;       // 0 / 32
    int wcol = (w >> 1) << 6;      // 0 / 64
    int quad = lane >> 4, l16 = lane & 15;

    f32x4 acc[2][4];
    const f32x4 z4 = {0.f, 0.f, 0.f, 0.f};
#pragma unroll
    for (int mt = 0; mt < 2; ++mt)
#pragma unroll
        for (int nt = 0; nt < 4; ++nt) acc[mt][nt] = z4;

    // A stage: q = w (k-octet), m = lane (row); one issue per thread
    int growA = row0 + lane;
    if (growA >= Nn) growA = Nn - 1;
    // B stage: 2 rounds; round r: q = 2r + (tid>>7), n = tid&127
    int qB = tid >> 7, nB = tid & 127;

    auto stage = [&](int ks, int buf) {
        const unsigned short* ga = parts[ks >> 7] + ((size_t)growA << 7) + (ks & 127) + (w << 3);
        __builtin_amdgcn_global_load_lds(
            (const __attribute__((address_space(1))) void*)ga,
            (__attribute__((address_space(3))) void*)&Als[buf][((w << 6) + lane) << 3], 16, 0, 0);
#pragma unroll
        for (int r = 0; r < 2; ++r) {
            int q = 2 * r + qB;
            int koG = (ks >> 3) + q;
            const unsigned short* gb = Wb + ((size_t)(koG * Ntot + n0c + nB) << 3);
            __builtin_amdgcn_global_load_lds(
                (const __attribute__((address_space(1))) void*)gb,
                (__attribute__((address_space(3))) void*)&Bls[buf][((q << 7) + nB) << 3], 16, 0, 0);
        }
    };

    stage(0, 0);
    __syncthreads();
    int buf = 0;
    for (int ks = 0; ks < 512; ks += 32, buf ^= 1) {
        if (ks + 32 < 512) stage(ks + 32, buf ^ 1);

        bf16x8s af[2], bfr[4];
#pragma unroll
        for (int mt = 0; mt < 2; ++mt)
            af[mt] = *reinterpret_cast<const bf16x8s*>(
                &Als[buf][((quad << 6) + wrow + (mt << 4) + l16) << 3]);
#pragma unroll
        for (int nt = 0; nt < 4; ++nt)
            bfr[nt] = *reinterpret_cast<const bf16x8s*>(
                &Bls[buf][((quad << 7) + wcol + (nt << 4) + l16) << 3]);
#pragma unroll
        for (int mt = 0; mt < 2; ++mt)
#pragma unroll
            for (int nt = 0; nt < 4; ++nt)
                acc[mt][nt] = __builtin_amdgcn_mfma_f32_16x16x32_bf16(
                    af[mt], bfr[nt], acc[mt][nt], 0, 0, 0);
        __syncthreads();
    }

    // Epilogue: row = row0 + wrow + mt*16 + quad*4 + reg; col = n0c + wcol + nt*16 + l16
#pragma unroll
    for (int mt = 0; mt < 2; ++mt) {
#pragma unroll
        for (int reg = 0; reg < 4; ++reg) {
            int row = row0 + wrow + (mt << 4) + (quad << 2) + reg;
            if (row >= Nn) continue;
#pragma unroll
            for (int nt = 0; nt < 4; ++nt) {
                int col = n0c + wcol + (nt << 4) + l16;
                float val = acc[mt][nt][reg] + bias[col];
                if (mode == 0) {
                    float sg = sigmoidf_(val);
                    int c = col & 127;
                    size_t o = ((size_t)row << 7) + c;
                    if (col < 128)
                        outb[o] = f2bf(sg * hfull[o]);   // rh = r*h (bf16)
                    else
                        outf[o] = sg;                    // u (f32)
                } else {
                    float cv = sigmoidf_(val);
                    size_t o = ((size_t)row << 7) + col;
                    float uu = uin[o];
                    float hh = hfull[o];
                    float hn = uu * hh + (1.0f - uu) * cv;
                    outf[o] = hn;
                    if (outf2) outf2[o] = hn;
                    outb[o] = f2bf(hn);                  // next layer's xb
                }
            }
        }
    }
}

// ---------------------------------------------------------------------------
extern "C" void kernel_launch(void* const* d_in, const int* in_sizes, int n_in,
                              void* d_out, int out_size, void* d_ws, size_t ws_size,
                              hipStream_t stream) {
    const float* x      = (const float*)d_in[0];
    const float* hidden = (const float*)d_in[1];
    const int*   src    = (const int*)d_in[2];
    const int*   dst    = (const int*)d_in[3];
    const float* ew     = (const float*)d_in[4];
    const float* Wself  = (const float*)d_in[5];
    const float* Wneigh = (const float*)d_in[6];
    const float* bias   = (const float*)d_in[7];
    float* out = (float*)d_out;

    int N = in_sizes[0] / F;  // 50000
    int E = in_sizes[2];      // 800000
    size_t NF = (size_t)N * F;

    char* p = (char*)d_ws;
    auto alloc = [&](size_t bytes) { char* r = p; p += (bytes + 255) & ~255ull; return r; };
    unsigned short* xb0    = (unsigned short*)alloc(NF * 2);
    unsigned short* xb1    = (unsigned short*)alloc(NF * 2);
    unsigned short* hb     = (unsigned short*)alloc(2 * NF * 2);
    unsigned short* agg_xb = (unsigned short*)alloc(NF * 2);
    unsigned short* agg_hb = (unsigned short*)alloc(NF * 2);
    unsigned short* agg_rb = (unsigned short*)alloc(NF * 2);
    unsigned short* rhb    = (unsigned short*)alloc(NF * 2);
    float*          u      = (float*)alloc(NF * 4);
    unsigned short* W1b    = (unsigned short*)alloc(2 * 64 * 256 * 8 * 2);
    unsigned short* W2b    = (unsigned short*)alloc(2 * 64 * 128 * 8 * 2);
    int2*           es     = (int2*)alloc((size_t)E * 8);
    int*            cnt    = (int*)alloc((size_t)N * 4);
    int*            offs   = (int*)alloc(((size_t)N + 1) * 4);
    int*            cursor = (int*)alloc((size_t)N * 4);

    pack_w_bf16<<<dim3(1536), dim3(256), 0, stream>>>(Wself, Wneigh, W1b, W2b);
    cvt_bf16<<<dim3((int)(NF / 4 + 255) / 256, 1), dim3(256), 0, stream>>>(x, xb0, (int)(NF / 4));
    cvt_bf16<<<dim3((int)(2 * NF / 4 + 255) / 256, 1), dim3(256), 0, stream>>>(hidden, hb, (int)(2 * NF / 4));

    hipMemsetAsync(cnt, 0, (size_t)N * sizeof(int), stream);
    int eBlocks = (E + 255) / 256;
    hist_dst<<<dim3(eBlocks), dim3(256), 0, stream>>>(dst, cnt, E);
    scan_offs<<<dim3(1), dim3(1024), 0, stream>>>(cnt, offs, cursor, N);
    scatter_edges<<<dim3(eBlocks), dim3(256), 0, stream>>>(src, dst, ew, cursor, es, E);

    float* out_x  = out;
    float* out_h1 = out + NF;
    float* out_h2 = out + 2 * NF;

    int aggBlocks = (N + 7) / 8;
    int mBlocks = (N + 63) / 64;
    for (int l = 0; l < NLAYERS; ++l) {
        const unsigned short* xbL = (l == 0) ? xb0 : xb1;
        const unsigned short* hbL = hb + (size_t)l * NF;
        const float* hL = hidden + (size_t)l * NF;
        const float* biasL = bias + (size_t)l * 384;

        agg_csr2_b<<<dim3(aggBlocks), dim3(256), 0, stream>>>(xbL, hbL, es, offs,
                                                              agg_xb, agg_hb, N);

        gemm_mfma<<<dim3(mBlocks, 2), dim3(256), 0, stream>>>(
            xbL, hbL, agg_xb, agg_hb,
            W1b + (size_t)l * 64 * 256 * 8, biasL, hL, nullptr,
            rhb, u, nullptr, N, 256, 0);

        agg_csr1_b<<<dim3(aggBlocks), dim3(256), 0, stream>>>(rhb, es, offs, agg_rb, N);

        float* o1 = (l == 0) ? out_h1 : out_h2;
        float* o2 = (l == NLAYERS - 1) ? out_x : nullptr;
        unsigned short* xbN = (l == 0) ? xb1 : xb0;  // l==1's outb is a dead scratch
        gemm_mfma<<<dim3(mBlocks, 1), dim3(256), 0, stream>>>(
            xbL, rhb, agg_xb, agg_rb,
            W2b + (size_t)l * 64 * 128 * 8, biasL + 256, hL, u,
            xbN, o1, o2, N, 128, 1);
    }
}

// Round 2
// 608.463 us; speedup vs baseline: 1.0945x; 1.0945x over previous
//
#include <hip/hip_runtime.h>
#include <math.h>

#define F 128
#define NLAYERS 2

typedef __attribute__((ext_vector_type(8))) short bf16x8s;
typedef __attribute__((ext_vector_type(8))) unsigned short u16x8;
typedef __attribute__((ext_vector_type(4))) float f32x4;

__device__ __forceinline__ float sigmoidf_(float x) { return 1.0f / (1.0f + expf(-x)); }

__device__ __forceinline__ unsigned short f2bf(float f) {
    unsigned int u = __float_as_uint(f);
    u += 0x7fffu + ((u >> 16) & 1u);  // RNE
    return (unsigned short)(u >> 16);
}
__device__ __forceinline__ float bf2f(unsigned short s) {
    return __uint_as_float(((unsigned int)s) << 16);
}

// ---------------------------------------------------------------------------
// Weight pack: f32 [L][3][256][128] -> bf16 k-octet layout.
//  W1b [L][64][256][8]: gates (r|u) as 256 cols, K=512 parts (x,h,agg_x,agg_h)
//  W2b [L][64][128][8]: gate c, K parts (x, rh, agg_x, agg_rh)
// ---------------------------------------------------------------------------
__global__ void pack_w_bf16(const float* __restrict__ Ws, const float* __restrict__ Wn,
                            unsigned short* __restrict__ W1b, unsigned short* __restrict__ W2b) {
    int t = blockIdx.x * blockDim.x + threadIdx.x;
    const int n1 = 2 * 64 * 256 * 8;  // 262144
    if (t < n1) {
        int j = t & 7, n = (t >> 3) & 255, ko = (t >> 11) & 63, l = t >> 17;
        int k = ko * 8 + j;
        int p = k >> 7, r = k & 127, g = n >> 7, c = n & 127;
        const float* W = (p < 2) ? Ws : Wn;
        W1b[t] = f2bf(W[(((l * 3 + g) * 256) + ((p & 1) * 128 + r)) * 128 + c]);
    } else {
        int t2 = t - n1;
        if (t2 >= 2 * 64 * 128 * 8) return;
        int j = t2 & 7, n = (t2 >> 3) & 127, ko = (t2 >> 10) & 63, l = t2 >> 16;
        int k = ko * 8 + j;
        int p = k >> 7, r = k & 127;
        const float* W = (p < 2) ? Ws : Wn;
        W2b[t2] = f2bf(W[(((l * 3 + 2) * 256) + ((p & 1) * 128 + r)) * 128 + n]);
    }
}

// f32 -> bf16 into interleaved xh table: out row stride 256 elements.
// t indexes groups of 4 floats; row = t>>5, col4 = t&31 (128 cols per part).
__global__ void cvt_bf16_i(const float* __restrict__ in, unsigned short* __restrict__ out, int n4) {
    int t = blockIdx.x * blockDim.x + threadIdx.x;
    if (t >= n4) return;
    float4 v = reinterpret_cast<const float4*>(in)[t];
    ushort4 o;
    o.x = f2bf(v.x); o.y = f2bf(v.y); o.z = f2bf(v.z); o.w = f2bf(v.w);
    *reinterpret_cast<ushort4*>(out + (((size_t)(t >> 5)) << 8) + ((t & 31) << 2)) = o;
}

// ---------------------------------------------------------------------------
// CSR build
// ---------------------------------------------------------------------------
__global__ void hist_dst(const int* __restrict__ dst, int* __restrict__ cnt, int E) {
    int e = blockIdx.x * blockDim.x + threadIdx.x;
    if (e < E) atomicAdd(&cnt[dst[e]], 1);
}

// Parallel exclusive scan, 3 kernels: per-block scan -> top scan -> add base.
__global__ __launch_bounds__(1024) void scan_blk(const int* __restrict__ cnt,
                                                 int* __restrict__ offs,
                                                 int* __restrict__ bsum, int n) {
    __shared__ int wsum[16];
    int tid = threadIdx.x, lane = tid & 63, wid = tid >> 6;
    int i = blockIdx.x * 1024 + tid;
    int v = (i < n) ? cnt[i] : 0;
    int incl = v;
#pragma unroll
    for (int off = 1; off < 64; off <<= 1) {
        int t = __shfl_up(incl, off, 64);
        if (lane >= off) incl += t;
    }
    if (lane == 63) wsum[wid] = incl;
    __syncthreads();
    if (wid == 0) {
        int s = (lane < 16) ? wsum[lane] : 0;
#pragma unroll
        for (int off = 1; off < 16; off <<= 1) {
            int t = __shfl_up(s, off, 64);
            if (lane >= off) s += t;
        }
        if (lane < 16) wsum[lane] = s;
    }
    __syncthreads();
    int wbase = (wid > 0) ? wsum[wid - 1] : 0;
    if (i < n) offs[i] = wbase + incl - v;
    if (tid == 1023) bsum[blockIdx.x] = wbase + incl;  // block total
}

__global__ __launch_bounds__(1024) void scan_tops(int* __restrict__ bsum, int nb,
                                                  int* __restrict__ total_out) {
    __shared__ int wsum[16];
    int tid = threadIdx.x, lane = tid & 63, wid = tid >> 6;
    int v = (tid < nb) ? bsum[tid] : 0;
    int incl = v;
#pragma unroll
    for (int off = 1; off < 64; off <<= 1) {
        int t = __shfl_up(incl, off, 64);
        if (lane >= off) incl += t;
    }
    if (lane == 63) wsum[wid] = incl;
    __syncthreads();
    if (wid == 0) {
        int s = (lane < 16) ? wsum[lane] : 0;
#pragma unroll
        for (int off = 1; off < 16; off <<= 1) {
            int t = __shfl_up(s, off, 64);
            if (lane >= off) s += t;
        }
        if (lane < 16) wsum[lane] = s;
    }
    __syncthreads();
    int wbase = (wid > 0) ? wsum[wid - 1] : 0;
    if (tid < nb) bsum[tid] = wbase + incl - v;  // exclusive base per block
    if (tid == 1023) *total_out = wbase + incl;  // grand total -> offs[n]
}

__global__ __launch_bounds__(1024) void scan_add(const int* __restrict__ bsum,
                                                 int* __restrict__ offs,
                                                 int* __restrict__ cursor, int n) {
    int i = blockIdx.x * 1024 + threadIdx.x;
    if (i >= n) return;
    int o = offs[i] + bsum[blockIdx.x];
    offs[i] = o;
    cursor[i] = o;
}

__global__ void scatter_edges(const int* __restrict__ src, const int* __restrict__ dst,
                              const float* __restrict__ ew, int* __restrict__ cursor,
                              int2* __restrict__ es, int E) {
    int e = blockIdx.x * blockDim.x + threadIdx.x;
    if (e >= E) return;
    int d = dst[e];
    int p = atomicAdd(&cursor[d], 1);
    es[p] = make_int2(src[e], __float_as_int(ew[e]));
}

// ---------------------------------------------------------------------------
// CSR aggregation over interleaved xh[N][256] bf16: 32 lanes/node, each lane
// one 16B (ushort8) gather per edge; lanes 0-15 = x part, 16-31 = h part.
// Unroll-4 edges, dual accumulator sets. f32 accumulate, bf16 store.
// ---------------------------------------------------------------------------
__global__ __launch_bounds__(256) void agg_csr2_i(
    const unsigned short* __restrict__ XH,
    const int2* __restrict__ es, const int* __restrict__ offs,
    unsigned short* __restrict__ agg0, unsigned short* __restrict__ agg1, int N) {
    int node = blockIdx.x * 8 + (threadIdx.x >> 5);
    if (node >= N) return;
    int lane = threadIdx.x & 31;
    int beg = offs[node], end = offs[node + 1];
    float a0[8] = {0, 0, 0, 0, 0, 0, 0, 0};
    float a1[8] = {0, 0, 0, 0, 0, 0, 0, 0};
    int loff = lane << 3;
    int i = beg;
    for (; i + 3 < end; i += 4) {
        int2 e0 = es[i], e1 = es[i + 1], e2 = es[i + 2], e3 = es[i + 3];
        u16x8 v0 = *reinterpret_cast<const u16x8*>(XH + (((size_t)e0.x) << 8) + loff);
        u16x8 v1 = *reinterpret_cast<const u16x8*>(XH + (((size_t)e1.x) << 8) + loff);
        u16x8 v2 = *reinterpret_cast<const u16x8*>(XH + (((size_t)e2.x) << 8) + loff);
        u16x8 v3 = *reinterpret_cast<const u16x8*>(XH + (((size_t)e3.x) << 8) + loff);
        float w0 = __int_as_float(e0.y), w1 = __int_as_float(e1.y);
        float w2 = __int_as_float(e2.y), w3 = __int_as_float(e3.y);
#pragma unroll
        for (int j = 0; j < 8; ++j) {
            a0[j] += w0 * bf2f(v0[j]);
            a1[j] += w1 * bf2f(v1[j]);
            a0[j] += w2 * bf2f(v2[j]);
            a1[j] += w3 * bf2f(v3[j]);
        }
    }
    for (; i < end; ++i) {
        int2 e0 = es[i];
        float w0 = __int_as_float(e0.y);
        u16x8 v0 = *reinterpret_cast<const u16x8*>(XH + (((size_t)e0.x) << 8) + loff);
#pragma unroll
        for (int j = 0; j < 8; ++j) a0[j] += w0 * bf2f(v0[j]);
    }
    u16x8 o;
#pragma unroll
    for (int j = 0; j < 8; ++j) o[j] = f2bf(a0[j] + a1[j]);
    unsigned short* op = (lane < 16)
        ? (agg0 + (((size_t)node) << 7) + (lane << 3))
        : (agg1 + (((size_t)node) << 7) + ((lane & 15) << 3));
    *reinterpret_cast<u16x8*>(op) = o;
}

// Single-table CSR aggregation (rh, [N][128] bf16): 32 lanes x 8B, unroll-4.
__global__ __launch_bounds__(256) void agg_csr1_b(
    const unsigned short* __restrict__ V0,
    const int2* __restrict__ es, const int* __restrict__ offs,
    unsigned short* __restrict__ agg0, int N) {
    int node = blockIdx.x * 8 + (threadIdx.x >> 5);
    if (node >= N) return;
    int lane = threadIdx.x & 31;
    int beg = offs[node], end = offs[node + 1];
    float p0[4] = {0, 0, 0, 0}, p1[4] = {0, 0, 0, 0};
    int loff = lane << 2;
    int i = beg;
    for (; i + 3 < end; i += 4) {
        int2 e0 = es[i], e1 = es[i + 1], e2 = es[i + 2], e3 = es[i + 3];
        ushort4 x0 = *reinterpret_cast<const ushort4*>(V0 + (((size_t)e0.x) << 7) + loff);
        ushort4 x1 = *reinterpret_cast<const ushort4*>(V0 + (((size_t)e1.x) << 7) + loff);
        ushort4 x2 = *reinterpret_cast<const ushort4*>(V0 + (((size_t)e2.x) << 7) + loff);
        ushort4 x3 = *reinterpret_cast<const ushort4*>(V0 + (((size_t)e3.x) << 7) + loff);
        float w0 = __int_as_float(e0.y), w1 = __int_as_float(e1.y);
        float w2 = __int_as_float(e2.y), w3 = __int_as_float(e3.y);
        p0[0] += w0 * bf2f(x0.x); p0[1] += w0 * bf2f(x0.y);
        p0[2] += w0 * bf2f(x0.z); p0[3] += w0 * bf2f(x0.w);
        p1[0] += w1 * bf2f(x1.x); p1[1] += w1 * bf2f(x1.y);
        p1[2] += w1 * bf2f(x1.z); p1[3] += w1 * bf2f(x1.w);
        p0[0] += w2 * bf2f(x2.x); p0[1] += w2 * bf2f(x2.y);
        p0[2] += w2 * bf2f(x2.z); p0[3] += w2 * bf2f(x2.w);
        p1[0] += w3 * bf2f(x3.x); p1[1] += w3 * bf2f(x3.y);
        p1[2] += w3 * bf2f(x3.z); p1[3] += w3 * bf2f(x3.w);
    }
    for (; i < end; ++i) {
        int2 e0 = es[i];
        float w0 = __int_as_float(e0.y);
        ushort4 x0 = *reinterpret_cast<const ushort4*>(V0 + (((size_t)e0.x) << 7) + loff);
        p0[0] += w0 * bf2f(x0.x); p0[1] += w0 * bf2f(x0.y);
        p0[2] += w0 * bf2f(x0.z); p0[3] += w0 * bf2f(x0.w);
    }
    size_t ob = (((size_t)node) << 7) + loff;
    ushort4 o0;
    o0.x = f2bf(p0[0] + p1[0]); o0.y = f2bf(p0[1] + p1[1]);
    o0.z = f2bf(p0[2] + p1[2]); o0.w = f2bf(p0[3] + p1[3]);
    *reinterpret_cast<ushort4*>(agg0 + ob) = o0;
}

// ---------------------------------------------------------------------------
// MFMA GEMM, 64x128 tile, 4 waves (2x2), 2x4 frags/wave, double-buffered LDS.
// A = 4 parts, parts 0/1 have element row strides sA0/sA1 (256 for xh,
// 128 for plain tables); parts 2/3 fixed stride 128.
// B = Wb bf16 k-octet layout [K/8][Ntot][8].
// mode 0 (ru): col<128 -> rhb = bf16(sigmoid*h); col>=128 -> u = sigmoid (f32)
// mode 1 (c):  c = sigmoid; hn = u*h+(1-u)*c -> outf (+outf2),
//              outb row shift obsh (7 plain / 8 = xh cols 0-127)
// ---------------------------------------------------------------------------
__global__ __launch_bounds__(256) void gemm_mfma(
    const unsigned short* __restrict__ A0, const unsigned short* __restrict__ A1,
    const unsigned short* __restrict__ A2, const unsigned short* __restrict__ A3,
    int sA0, int sA1, int obsh,
    const unsigned short* __restrict__ Wb, const float* __restrict__ bias,
    const float* __restrict__ hfull, const float* __restrict__ uin,
    unsigned short* __restrict__ outb, float* __restrict__ outf,
    float* __restrict__ outf2, int Nn, int Ntot, int mode) {
    __shared__ __align__(16) unsigned short Als[2][4 * 64 * 8];   // [buf][q][m][8]  4KB x2
    __shared__ __align__(16) unsigned short Bls[2][4 * 128 * 8];  // [buf][q][n][8]  8KB x2
    const unsigned short* parts[4] = {A0, A1, A2, A3};

    int tid = threadIdx.x;
    int row0 = blockIdx.x * 64;
    int n0c = blockIdx.y * 128;
    int lane = tid & 63;
    int w = tid >> 6;
    int wrow = (w & 1) << 5;       // 0 / 32
    int wcol = (w >> 1) << 6;      // 0 / 64
    int quad = lane >> 4, l16 = lane & 15;

    f32x4 acc[2][4];
    const f32x4 z4 = {0.f, 0.f, 0.f, 0.f};
#pragma unroll
    for (int mt = 0; mt < 2; ++mt)
#pragma unroll
        for (int nt = 0; nt < 4; ++nt) acc[mt][nt] = z4;

    // A stage: q = w (k-octet), m = lane (row); one issue per thread
    int growA = row0 + lane;
    if (growA >= Nn) growA = Nn - 1;
    // B stage: 2 rounds; round r: q = 2r + (tid>>7), n = tid&127
    int qB = tid >> 7, nB = tid & 127;

    auto stage = [&](int ks, int buf) {
        int p = ks >> 7;
        size_t roff = (p == 0) ? (size_t)growA * (size_t)sA0
                    : (p == 1) ? (size_t)growA * (size_t)sA1
                               : ((size_t)growA << 7);
        const unsigned short* ga = parts[p] + roff + (ks & 127) + (w << 3);
        __builtin_amdgcn_global_load_lds(
            (const __attribute__((address_space(1))) void*)ga,
            (__attribute__((address_space(3))) void*)&Als[buf][((w << 6) + lane) << 3], 16, 0, 0);
#pragma unroll
        for (int r = 0; r < 2; ++r) {
            int q = 2 * r + qB;
            int koG = (ks >> 3) + q;
            const unsigned short* gb = Wb + ((size_t)(koG * Ntot + n0c + nB) << 3);
            __builtin_amdgcn_global_load_lds(
                (const __attribute__((address_space(1))) void*)gb,
                (__attribute__((address_space(3))) void*)&Bls[buf][((q << 7) + nB) << 3], 16, 0, 0);
        }
    };

    stage(0, 0);
    __syncthreads();
    int buf = 0;
    for (int ks = 0; ks < 512; ks += 32, buf ^= 1) {
        if (ks + 32 < 512) stage(ks + 32, buf ^ 1);

        bf16x8s af[2], bfr[4];
#pragma unroll
        for (int mt = 0; mt < 2; ++mt)
            af[mt] = *reinterpret_cast<const bf16x8s*>(
                &Als[buf][((quad << 6) + wrow + (mt << 4) + l16) << 3]);
#pragma unroll
        for (int nt = 0; nt < 4; ++nt)
            bfr[nt] = *reinterpret_cast<const bf16x8s*>(
                &Bls[buf][((quad << 7) + wcol + (nt << 4) + l16) << 3]);
#pragma unroll
        for (int mt = 0; mt < 2; ++mt)
#pragma unroll
            for (int nt = 0; nt < 4; ++nt)
                acc[mt][nt] = __builtin_amdgcn_mfma_f32_16x16x32_bf16(
                    af[mt], bfr[nt], acc[mt][nt], 0, 0, 0);
        __syncthreads();
    }

    // Epilogue: row = row0 + wrow + mt*16 + quad*4 + reg; col = n0c + wcol + nt*16 + l16
#pragma unroll
    for (int mt = 0; mt < 2; ++mt) {
#pragma unroll
        for (int reg = 0; reg < 4; ++reg) {
            int row = row0 + wrow + (mt << 4) + (quad << 2) + reg;
            if (row >= Nn) continue;
#pragma unroll
            for (int nt = 0; nt < 4; ++nt) {
                int col = n0c + wcol + (nt << 4) + l16;
                float val = acc[mt][nt][reg] + bias[col];
                if (mode == 0) {
                    float sg = sigmoidf_(val);
                    int c = col & 127;
                    size_t o = ((size_t)row << 7) + c;
                    if (col < 128)
                        outb[o] = f2bf(sg * hfull[o]);   // rh = r*h (bf16)
                    else
                        outf[o] = sg;                    // u (f32)
                } else {
                    float cv = sigmoidf_(val);
                    size_t o = ((size_t)row << 7) + col;
                    float uu = uin[o];
                    float hh = hfull[o];
                    float hn = uu * hh + (1.0f - uu) * cv;
                    outf[o] = hn;
                    if (outf2) outf2[o] = hn;
                    outb[((size_t)row << obsh) + col] = f2bf(hn);  // next layer's x
                }
            }
        }
    }
}

// ---------------------------------------------------------------------------
extern "C" void kernel_launch(void* const* d_in, const int* in_sizes, int n_in,
                              void* d_out, int out_size, void* d_ws, size_t ws_size,
                              hipStream_t stream) {
    const float* x      = (const float*)d_in[0];
    const float* hidden = (const float*)d_in[1];
    const int*   src    = (const int*)d_in[2];
    const int*   dst    = (const int*)d_in[3];
    const float* ew     = (const float*)d_in[4];
    const float* Wself  = (const float*)d_in[5];
    const float* Wneigh = (const float*)d_in[6];
    const float* bias   = (const float*)d_in[7];
    float* out = (float*)d_out;

    int N = in_sizes[0] / F;  // 50000
    int E = in_sizes[2];      // 800000
    size_t NF = (size_t)N * F;

    char* p = (char*)d_ws;
    auto alloc = [&](size_t bytes) { char* r = p; p += (bytes + 255) & ~255ull; return r; };
    unsigned short* xh0    = (unsigned short*)alloc(2 * NF * 2);  // [N][256] interleaved x|h
    unsigned short* xh1    = (unsigned short*)alloc(2 * NF * 2);  // [N][256] interleaved x|h
    unsigned short* agg_xb = (unsigned short*)alloc(NF * 2);
    unsigned short* agg_hb = (unsigned short*)alloc(NF * 2);
    unsigned short* agg_rb = (unsigned short*)alloc(NF * 2);
    unsigned short* rhb    = (unsigned short*)alloc(NF * 2);
    float*          u      = (float*)alloc(NF * 4);
    unsigned short* W1b    = (unsigned short*)alloc(2 * 64 * 256 * 8 * 2);
    unsigned short* W2b    = (unsigned short*)alloc(2 * 64 * 128 * 8 * 2);
    int2*           es     = (int2*)alloc((size_t)E * 8);
    int*            cnt    = (int*)alloc((size_t)N * 4);
    int*            offs   = (int*)alloc(((size_t)N + 1) * 4);
    int*            cursor = (int*)alloc((size_t)N * 4);
    int*            bsum   = (int*)alloc(1024 * 4);

    pack_w_bf16<<<dim3(1536), dim3(256), 0, stream>>>(Wself, Wneigh, W1b, W2b);
    int n4 = (int)(NF / 4);
    int cblk = (n4 + 255) / 256;
    cvt_bf16_i<<<dim3(cblk), dim3(256), 0, stream>>>(x, xh0, n4);                 // x -> xh0[:,0:128]
    cvt_bf16_i<<<dim3(cblk), dim3(256), 0, stream>>>(hidden, xh0 + 128, n4);      // h0 -> xh0[:,128:256]
    cvt_bf16_i<<<dim3(cblk), dim3(256), 0, stream>>>(hidden + NF, xh1 + 128, n4); // h1 -> xh1[:,128:256]

    hipMemsetAsync(cnt, 0, (size_t)N * sizeof(int), stream);
    int eBlocks = (E + 255) / 256;
    hist_dst<<<dim3(eBlocks), dim3(256), 0, stream>>>(dst, cnt, E);
    int nb = (N + 1023) / 1024;  // 49 (must be <= 1024)
    scan_blk<<<dim3(nb), dim3(1024), 0, stream>>>(cnt, offs, bsum, N);
    scan_tops<<<dim3(1), dim3(1024), 0, stream>>>(bsum, nb, offs + N);
    scan_add<<<dim3(nb), dim3(1024), 0, stream>>>(bsum, offs, cursor, N);
    scatter_edges<<<dim3(eBlocks), dim3(256), 0, stream>>>(src, dst, ew, cursor, es, E);

    float* out_x  = out;
    float* out_h1 = out + NF;
    float* out_h2 = out + 2 * NF;

    int aggBlocks = (N + 7) / 8;
    int mBlocks = (N + 63) / 64;
    for (int l = 0; l < NLAYERS; ++l) {
        unsigned short* xhL = (l == 0) ? xh0 : xh1;
        const float* hL = hidden + (size_t)l * NF;
        const float* biasL = bias + (size_t)l * 384;

        agg_csr2_i<<<dim3(aggBlocks), dim3(256), 0, stream>>>(xhL, es, offs,
                                                              agg_xb, agg_hb, N);

        // gates r,u: A = [x (xh,256), h (xh+128,256), agg_x (128), agg_h (128)]
        gemm_mfma<<<dim3(mBlocks, 2), dim3(256), 0, stream>>>(
            xhL, xhL + 128, agg_xb, agg_hb, 256, 256, 7,
            W1b + (size_t)l * 64 * 256 * 8, biasL, hL, nullptr,
            rhb, u, nullptr, N, 256, 0);

        agg_csr1_b<<<dim3(aggBlocks), dim3(256), 0, stream>>>(rhb, es, offs, agg_rb, N);

        float* o1 = (l == 0) ? out_h1 : out_h2;
        float* o2 = (l == NLAYERS - 1) ? out_x : nullptr;
        // l==0: outb -> xh1 cols 0:128 (stride 256, obsh=8) = next layer's x.
        // l==1: outb dead; write into agg_rb (each block writes only rows it
        //       alone stages, after its last read) with obsh=7.
        unsigned short* obN = (l == 0) ? xh1 : agg_rb;
        int obsh = (l == 0) ? 8 : 7;
        gemm_mfma<<<dim3(mBlocks, 1), dim3(256), 0, stream>>>(
            xhL, rhb, agg_xb, agg_rb, 256, 128, obsh,
            W2b + (size_t)l * 64 * 128 * 8, biasL + 256, hL, u,
            obN, o1, o2, N, 128, 1);
    }
}